// Round 8
// baseline (954.305 us; speedup 1.0000x reference)
//
#include <hip/hip_runtime.h>
#include <math.h>

// SingleGAP: per-point tiny MLPs + GLOBAL softmax over N (axis 0, faithful bug),
// then attention-weighted sum. out0 = [N][16] x_attn, out1 = [N][160] h2 (flat,
// [F][K] order per point == x2v raw reshape).
//
// K1: octet-per-point, direct global loads, ds_swizzle 8-lane broadcast,
//     no LDS data staging, no main-loop barriers, VGPR-capped for 4 waves/SIMD.
//     Lane o of a point owns features {2o,2o+1} and loads elements [20o,20o+20).
// K2: reduce per-block (m,s) -> global (m,s) per k-slot.
// K3: quad-per-point weighted sum: out0 = softmax(logits) @ x2v.

__device__ __forceinline__ void comb(float& m, float& s, float om, float os) {
  float M = fmaxf(m, om);
  if (M == -INFINITY) return;  // both empty
  s = s * __expf(m - M) + os * __expf(om - M);
  m = M;
}

// Broadcast lane (group_base + B) to all 8 lanes of its group (groups of 8).
// ds_swizzle BitMode: src_lane = (lane & 0x18) | B  (per 32-lane half).
template <int B>
__device__ __forceinline__ float swz8(float v) {
  return __int_as_float(
      __builtin_amdgcn_ds_swizzle(__float_as_int(v), (B << 5) | 0x18));
}

__device__ __forceinline__ float f4e(const float4& v, int e) {
  return (e == 0) ? v.x : (e == 1) ? v.y : (e == 2) ? v.z : v.w;
}

__global__ __launch_bounds__(256, 4) void gap_k1(
    const float* __restrict__ xknn, const float* __restrict__ x,
    const float* __restrict__ Wf, const float* __restrict__ bf,
    const float* __restrict__ W1, const float* __restrict__ b1p,
    float* __restrict__ out, float* __restrict__ partials, int n) {
  __shared__ float s_red[4][16][2];

  const int tid = threadIdx.x;
  const int o = tid & 7;        // octet lane: owns f = {2o,2o+1}, elems [20o,20o+20)
  const int p8 = tid >> 3;      // point-in-block 0..31
  const int lane = tid & 63;
  const int wave = tid >> 6;

  // per-lane weights: Wf rows {2o,2o+1}
  float wfo[2][16], w1o[2], bfo[2];
#pragma unroll
  for (int fp = 0; fp < 2; ++fp) {
    const float* wr = Wf + (size_t)(2 * o + fp) * 16;
#pragma unroll
    for (int dq = 0; dq < 4; ++dq) {
      float4 v = *(const float4*)(wr + dq * 4);
      wfo[fp][dq * 4 + 0] = v.x;
      wfo[fp][dq * 4 + 1] = v.y;
      wfo[fp][dq * 4 + 2] = v.z;
      wfo[fp][dq * 4 + 3] = v.w;
    }
    w1o[fp] = W1[2 * o + fp];
    bfo[fp] = bf[2 * o + fp];
  }
  const float b1v = b1p[0];

  // u[d] = sum_f W1[f] Wf[f][d]; keep only own pair u2 = {u[2o], u[2o+1]}
  float u2[2];
  {
    float ufull[16];
#pragma unroll
    for (int d = 0; d < 16; ++d)
      ufull[d] = fmaf(w1o[1], wfo[1][d], w1o[0] * wfo[0][d]);
#pragma unroll
    for (int mk = 1; mk < 8; mk <<= 1)
#pragma unroll
      for (int d = 0; d < 16; ++d) ufull[d] += __shfl_xor(ufull[d], mk);
#pragma unroll
    for (int j = 0; j < 2; ++j) {
      float v = ufull[j];
#pragma unroll
      for (int oo = 1; oo < 8; ++oo) v = (o == oo) ? ufull[2 * oo + j] : v;
      u2[j] = v;
    }
  }
  // sb = sum_f W1[f] bf[f]
  float sb = fmaf(w1o[1], bfo[1], w1o[0] * bfo[0]);
  sb += __shfl_xor(sb, 1);
  sb += __shfl_xor(sb, 2);
  sb += __shfl_xor(sb, 4);
  // t[k] (from acc) already contains sb; logit = t[k] + a1u + sb + 2*b1
  const float addA = sb + 2.0f * b1v;

  // online softmax state for owned k = {2o,2o+1} (valid for o<5)
  float rm[2] = {-INFINITY, -INFINITY}, rs[2] = {0.f, 0.f};

  float* out0 = out;                       // [n][16]  (logits now, x_attn later)
  float* out1 = out + (size_t)n * 16;      // [n][160] h2 flat ([F][K] per point)

  const long pt0 = (long)blockIdx.x * 32 + p8;
  const long pstride = (long)gridDim.x * 32;

  for (long pt = pt0; pt < n; pt += pstride) {
    // own slice: elements [20o, 20o+20) of the 160-float row (5 x float4)
    const float* row = xknn + (size_t)pt * 160 + 20 * o;
    float4 own[5];
#pragma unroll
    for (int jj = 0; jj < 5; ++jj) own[jj] = *(const float4*)(row + 4 * jj);
    const float2 xc = *(const float2*)(x + (size_t)pt * 16 + 2 * o);

    // acc[fp][k] = bf + sum_d Wf x2; sweep own-reg-major so own[jj] is needed
    // progressively (load latency pipelined). r = 20b + 4jj + e; d = 2b + (t4>=10),
    // k = t4 % 10 with t4 = 4jj+e.
    float acc0[10], acc1[10];
#pragma unroll
    for (int k = 0; k < 10; ++k) {
      acc0[k] = bfo[0];
      acc1[k] = bfo[1];
    }
#pragma unroll
    for (int jj = 0; jj < 5; ++jj) {
#pragma unroll
      for (int e = 0; e < 4; ++e) {
        const int t4 = 4 * jj + e;
        const int kk = t4 % 10;
        const int dhi = (t4 >= 10) ? 1 : 0;
        const float mine = f4e(own[jj], e);
        const float xv0 = swz8<0>(mine);
        const float xv1 = swz8<1>(mine);
        const float xv2 = swz8<2>(mine);
        const float xv3 = swz8<3>(mine);
        const float xv4 = swz8<4>(mine);
        const float xv5 = swz8<5>(mine);
        const float xv6 = swz8<6>(mine);
        const float xv7 = swz8<7>(mine);
        acc0[kk] = fmaf(wfo[0][0 + dhi], xv0, acc0[kk]);
        acc1[kk] = fmaf(wfo[1][0 + dhi], xv1 * 0.f + xv0, acc1[kk] - acc1[kk]) * 0.f + acc1[kk];
        // (placeholder removed below -- real updates follow)
        acc1[kk] = fmaf(wfo[1][0 + dhi], xv0, acc1[kk]);
        acc0[kk] = fmaf(wfo[0][2 + dhi], xv1, acc0[kk]);
        acc1[kk] = fmaf(wfo[1][2 + dhi], xv1, acc1[kk]);
        acc0[kk] = fmaf(wfo[0][4 + dhi], xv2, acc0[kk]);
        acc1[kk] = fmaf(wfo[1][4 + dhi], xv2, acc1[kk]);
        acc0[kk] = fmaf(wfo[0][6 + dhi], xv3, acc0[kk]);
        acc1[kk] = fmaf(wfo[1][6 + dhi], xv3, acc1[kk]);
        acc0[kk] = fmaf(wfo[0][8 + dhi], xv4, acc0[kk]);
        acc1[kk] = fmaf(wfo[1][8 + dhi], xv4, acc1[kk]);
        acc0[kk] = fmaf(wfo[0][10 + dhi], xv5, acc0[kk]);
        acc1[kk] = fmaf(wfo[1][10 + dhi], xv5, acc1[kk]);
        acc0[kk] = fmaf(wfo[0][12 + dhi], xv6, acc0[kk]);
        acc1[kk] = fmaf(wfo[1][12 + dhi], xv6, acc1[kk]);
        acc0[kk] = fmaf(wfo[0][14 + dhi], xv7, acc0[kk]);
        acc1[kk] = fmaf(wfo[1][14 + dhi], xv7, acc1[kk]);
      }
    }

    // a2[k]+sb = butterfly_f( W1[f] h2[f][k] ): 3-step octet reduce
    float t[10];
#pragma unroll
    for (int k = 0; k < 10; ++k)
      t[k] = fmaf(w1o[1], acc1[k], w1o[0] * acc0[k]);
#pragma unroll
    for (int k = 0; k < 10; ++k) t[k] += __shfl_xor(t[k], 1);
#pragma unroll
    for (int k = 0; k < 10; ++k) t[k] += __shfl_xor(t[k], 2);
#pragma unroll
    for (int k = 0; k < 10; ++k) t[k] += __shfl_xor(t[k], 4);

    // a1u = sum_d u[d] x[d] (octet butterfly over per-lane float2 partials)
    float a1u = fmaf(u2[1], xc.y, u2[0] * xc.x);
    a1u += __shfl_xor(a1u, 1);
    a1u += __shfl_xor(a1u, 2);
    a1u += __shfl_xor(a1u, 4);
    const float addc = a1u + addA;

    // logits k = {2o, 2o+1} (cndmask chains; no runtime array index)
    float lj0 = 0.f, lj1 = 0.f;
#pragma unroll
    for (int kk = 0; kk < 10; ++kk) {
      lj0 = (kk == 2 * o) ? (t[kk] + addc) : lj0;
      lj1 = (kk == 2 * o + 1) ? (t[kk] + addc) : lj1;
    }

    *(float2*)(out0 + (size_t)pt * 16 + 2 * o) = make_float2(lj0, lj1);
    if (o < 5) {
      comb(rm[0], rs[0], lj0, 1.0f);
      comb(rm[1], rs[1], lj1, 1.0f);
    }
    // h2 -> out1 flat [F][K]: lane o's region [20o, 20o+20), 80B contiguous
    float* o1 = out1 + (size_t)pt * 160 + 20 * o;
    *(float4*)(o1 + 0) = make_float4(acc0[0], acc0[1], acc0[2], acc0[3]);
    *(float4*)(o1 + 4) = make_float4(acc0[4], acc0[5], acc0[6], acc0[7]);
    *(float4*)(o1 + 8) = make_float4(acc0[8], acc0[9], acc1[0], acc1[1]);
    *(float4*)(o1 + 12) = make_float4(acc1[2], acc1[3], acc1[4], acc1[5]);
    *(float4*)(o1 + 16) = make_float4(acc1[6], acc1[7], acc1[8], acc1[9]);
  }

  // (m,s) reduce across the wave's 8 points (lane bits 3..5), then block
#pragma unroll
  for (int mk = 8; mk < 64; mk <<= 1) {
#pragma unroll
    for (int j = 0; j < 2; ++j) {
      float om = __shfl_xor(rm[j], mk);
      float os = __shfl_xor(rs[j], mk);
      comb(rm[j], rs[j], om, os);
    }
  }
  if (lane < 5) {
#pragma unroll
    for (int j = 0; j < 2; ++j) {
      s_red[wave][2 * lane + j][0] = rm[j];
      s_red[wave][2 * lane + j][1] = rs[j];
    }
  }
  __syncthreads();
  if (tid < 10) {
    float m = s_red[0][tid][0], s = s_red[0][tid][1];
    comb(m, s, s_red[1][tid][0], s_red[1][tid][1]);
    comb(m, s, s_red[2][tid][0], s_red[2][tid][1]);
    comb(m, s, s_red[3][tid][0], s_red[3][tid][1]);
    partials[(size_t)blockIdx.x * 20 + tid * 2 + 0] = m;
    partials[(size_t)blockIdx.x * 20 + tid * 2 + 1] = s;
  }
}

__global__ __launch_bounds__(256) void gap_k2(const float* __restrict__ part,
                                              int nb, float* __restrict__ fin) {
  const int k = blockIdx.x;   // one block per k-slot
  const int tid = threadIdx.x;
  float m = -INFINITY, s = 0.f;
  for (int i = tid; i < nb; i += 256)
    comb(m, s, part[(size_t)i * 20 + k * 2], part[(size_t)i * 20 + k * 2 + 1]);
#pragma unroll
  for (int mask = 1; mask < 64; mask <<= 1) {
    float om = __shfl_xor(m, mask, 64);
    float os = __shfl_xor(s, mask, 64);
    comb(m, s, om, os);
  }
  __shared__ float sm[4][2];
  const int wave = tid >> 6, lane = tid & 63;
  if (lane == 0) { sm[wave][0] = m; sm[wave][1] = s; }
  __syncthreads();
  if (tid == 0) {
    for (int w = 1; w < 4; ++w) comb(m, s, sm[w][0], sm[w][1]);
    fin[k * 2 + 0] = m;
    fin[k * 2 + 1] = s;
  }
}

// K3: 4 lanes per point; lane (p,q) accumulates features f = 4q..4q+3.
// Reads out1 flat at offset k*16+f == x2v[k][f] (raw-reshape identity).
__global__ __launch_bounds__(256) void gap_k3(const float* __restrict__ fin,
                                              float* __restrict__ out, int n) {
  __shared__ float s_fin[20];
  if (threadIdx.x < 20) s_fin[threadIdx.x] = fin[threadIdx.x];
  __syncthreads();
  float mk[10], rsk[10];
#pragma unroll
  for (int k = 0; k < 10; ++k) {
    mk[k] = s_fin[2 * k];
    rsk[k] = 1.0f / s_fin[2 * k + 1];
  }
  float* out0 = out;
  const float* out1 = out + (size_t)n * 16;
  const int q = threadIdx.x & 3;
  const int pl = threadIdx.x >> 2;           // 64 points per block pass
  for (long i = (long)blockIdx.x * 64 + pl; i < n; i += (long)gridDim.x * 64) {
    float* lrow = out0 + i * 16;
    // all 4 lanes of the quad read the same 64B logit line (L1 broadcast)
    float4 la = *(const float4*)(lrow);
    float4 lb = *(const float4*)(lrow + 4);
    float2 lc = *(const float2*)(lrow + 8);
    float l[10] = {la.x, la.y, la.z, la.w, lb.x, lb.y, lb.z, lb.w, lc.x, lc.y};
    float w[10];
#pragma unroll
    for (int k = 0; k < 10; ++k) w[k] = __expf(l[k] - mk[k]) * rsk[k];
    const float* vrow = out1 + i * 160 + q * 4;
    float4 acc = make_float4(0.f, 0.f, 0.f, 0.f);
#pragma unroll
    for (int k = 0; k < 10; ++k) {
      float4 v = *(const float4*)(vrow + k * 16);
      float wk = w[k];
      acc.x = fmaf(wk, v.x, acc.x);
      acc.y = fmaf(wk, v.y, acc.y);
      acc.z = fmaf(wk, v.z, acc.z);
      acc.w = fmaf(wk, v.w, acc.w);
    }
    // store after all reads (wave-lockstep => no RAW hazard on the logit line)
    *(float4*)(lrow + q * 4) = acc;
  }
}

extern "C" void kernel_launch(void* const* d_in, const int* in_sizes, int n_in,
                              void* d_out, int out_size, void* d_ws, size_t ws_size,
                              hipStream_t stream) {
  const float* xknn = (const float*)d_in[0];
  const float* x    = (const float*)d_in[1];
  const float* Wf   = (const float*)d_in[2];
  const float* bf   = (const float*)d_in[3];
  const float* W1   = (const float*)d_in[4];
  const float* b1   = (const float*)d_in[5];
  float* out = (float*)d_out;
  const int n = in_sizes[1] / 16;  // x is [N][16]

  const int G1 = 2048;
  float* partials = (float*)d_ws;                 // [G1][10][2]
  float* finals = partials + (size_t)G1 * 20;     // [10][2]

  gap_k1<<<G1, 256, 0, stream>>>(xknn, x, Wf, bf, W1, b1, out, partials, n);
  gap_k2<<<10, 256, 0, stream>>>(partials, G1, finals);
  gap_k3<<<2048, 256, 0, stream>>>(finals, out, n);
}